// Round 1
// 161.018 us; speedup vs baseline: 1.0388x; 1.0388x over previous
//
#include <hip/hip_runtime.h>

// Problem constants (fixed by reference: B=64, T=1024, D=256)
constexpr int Bn = 64;
constexpr int Tn = 1024;
constexpr int Dn = 256;

constexpr int TPB  = 256;   // 4 waves
constexpr int NBLK = Tn;    // one timestep per block; 1024 blocks = 4 blocks/CU, all resident

using short8 = __attribute__((ext_vector_type(8))) short;   // 8 bf16 (4 VGPRs) — MFMA A/B frag
using f32x16 = __attribute__((ext_vector_type(16))) float;  // MFMA 32x32 accumulator

__device__ __forceinline__ float dot4(const float4& a, const float4& b) {
    return a.x * b.x + a.y * b.y + a.z * b.z + a.w * b.w;
}

// fp32 -> bf16 bits, round-to-nearest-even (inputs are finite random normals; no NaN path needed)
__device__ __forceinline__ unsigned int bfbits(float x) {
    unsigned int u = __builtin_bit_cast(unsigned int, x);
    return (u + 0x7FFFu + ((u >> 16) & 1u)) >> 16;
}
__device__ __forceinline__ unsigned int pack_bf2(float lo, float hi) {
    return bfbits(lo) | (bfbits(hi) << 16);
}

__global__ __launch_bounds__(TPB, 4)   // cap VGPR at 128 -> 4 blocks/CU (LDS allows 4 at ~33 KB)
void cmfm_main(const float* __restrict__ fv, const float* __restrict__ fa,
               const int* __restrict__ labels, float* __restrict__ acc)
{
    // Half-D bf16 staging: 64 rows x 128 d = 64 uints/row (256 B). 16 KB per array.
    // 16B-slot XOR swizzle (slot ^ (row&15)) breaks the all-rows-same-bank pattern (G4).
    __shared__ __align__(16) unsigned int Vb[Bn * 64];
    __shared__ __align__(16) unsigned int Ab[Bn * 64];
    __shared__ float rvs[Bn], ras[Bn];
    __shared__ float wred[3][TPB / 64];

    const int tid  = threadIdx.x;
    const int row  = tid >> 2;      // loader row 0..63
    const int q    = tid & 3;       // quarter of the row (interleaved float4 ownership: d4 = q+4k)
    const int lane = tid & 63;
    const int wave = tid >> 6;

    const int lab = labels[row];
    const float4* __restrict__ fv4 = reinterpret_cast<const float4*>(fv);
    const float4* __restrict__ fa4 = reinterpret_cast<const float4*>(fa);

    const int t = blockIdx.x;
    const size_t base = ((size_t)row * Tn + t) * (Dn / 4);

    // MFMA geometry: 4 waves -> 2x2 quadrants of the 64x64 cross matrix
    const int i0   = (wave >> 1) * 32;
    const int j0   = (wave & 1) * 32;
    const int mrow = lane & 31;
    const int half = lane >> 5;
    const int rsx  = mrow & 15;                       // read swizzle key ((i0+mrow)&15 == mrow&15)
    const unsigned vrb = (unsigned)(i0 + mrow) * 64;  // uint index of V-row base
    const unsigned arb = (unsigned)(j0 + mrow) * 64;

    const int wsx = row & 15;                         // write swizzle key
    const unsigned wrb = (unsigned)row * 64;

    f32x16 C;
    #pragma unroll
    for (int r = 0; r < 16; ++r) C[r] = 0.f;

    float sqv = 0.f, sqa = 0.f, dva = 0.f;
    float rv = 0.f, ra = 0.f;

    #pragma unroll
    for (int h = 0; h < 2; ++h) {
        // ---- stage half h: 8 V + 8 A float4 per thread; norms in fp32; unscaled bf16 to LDS ----
        float4 v4[8], a4[8];
        #pragma unroll
        for (int k = 0; k < 8; ++k) v4[k] = fv4[base + q + 4 * (8 * h + k)];
        #pragma unroll
        for (int k = 0; k < 8; ++k) a4[k] = fa4[base + q + 4 * (8 * h + k)];

        #pragma unroll
        for (int k = 0; k < 8; ++k) {
            sqv += dot4(v4[k], v4[k]);
            sqa += dot4(a4[k], a4[k]);
            dva += dot4(v4[k], a4[k]);
        }

        #pragma unroll
        for (int k = 0; k < 8; ++k) {
            const int d4l  = q + 4 * k;          // 0..31 within this half
            const int slot = d4l >> 1;           // 16B slot (8 bf16)
            const unsigned idx = wrb + (unsigned)(((slot ^ wsx) << 2) + (d4l & 1) * 2);
            uint2 pv, pa;
            pv.x = pack_bf2(v4[k].x, v4[k].y); pv.y = pack_bf2(v4[k].z, v4[k].w);
            pa.x = pack_bf2(a4[k].x, a4[k].y); pa.y = pack_bf2(a4[k].z, a4[k].w);
            *reinterpret_cast<uint2*>(&Vb[idx]) = pv;   // ds_write_b64
            *reinterpret_cast<uint2*>(&Ab[idx]) = pa;
        }

        if (h == 1) {
            // full-row norms: reduce across the 4 quarter-threads (adjacent lanes)
            sqv += __shfl_xor(sqv, 1); sqv += __shfl_xor(sqv, 2);
            sqa += __shfl_xor(sqa, 1); sqa += __shfl_xor(sqa, 2);
            dva += __shfl_xor(dva, 1); dva += __shfl_xor(dva, 2);
            rv = 1.f / fmaxf(sqrtf(sqv), 1e-8f);
            ra = 1.f / fmaxf(sqrtf(sqa), 1e-8f);
            if (q == 0) { rvs[row] = rv; ras[row] = ra; }
        }
        __syncthreads();

        // ---- 8 MFMA k-steps (K=16 each) on this half; unscaled S accumulates over halves ----
        #pragma unroll
        for (int s = 0; s < 8; ++s) {
            const int slotl = s * 2 + half;   // lane-half owns k = 8*half..8*half+7 of each K=16 step
            const short8 av = *reinterpret_cast<const short8*>(&Vb[vrb + ((slotl ^ rsx) << 2)]);
            const short8 bv = *reinterpret_cast<const short8*>(&Ab[arb + ((slotl ^ rsx) << 2)]);
            C = __builtin_amdgcn_mfma_f32_32x32x16_bf16(av, bv, C, 0, 0, 0);
        }
        if (h == 0) __syncthreads();   // LDS fully consumed before half-1 overwrites
    }

    // ---- aligned-pair term (exact fp32, one lane per row) ----
    float pos_acc = 0.f, neg_acc = 0.f;
    if (q == 0) {
        const float cosd = dva * rv * ra;
        if (lab == 0) pos_acc = 1.f - cosd;   // d_bt = 1 - cos
        else          neg_acc = cosd;         // (1 - d_bt) = cos
    }

    // ---- cross term: fold rv_i * ra_j here; drop diagonal via verified C/D layout ----
    // C/D mapping (m74/m101): col = lane&31, row = (reg&3) + 8*(reg>>2) + 4*(lane>>5)
    const float raj = ras[j0 + mrow];
    float od = 0.f;
    #pragma unroll
    for (int r = 0; r < 16; ++r) {
        const int ri = (r & 3) + 8 * (r >> 2) + 4 * half;
        float c = C[r];
        if (i0 == j0 && ri == mrow) c = 0.f;          // i == j diagonal
        od += rvs[i0 + ri] * raj * c;
    }

    // ---- block reduce + 3 atomics (padded to separate cache lines) ----
    #pragma unroll
    for (int off = 1; off < 64; off <<= 1) {
        pos_acc += __shfl_xor(pos_acc, off);
        neg_acc += __shfl_xor(neg_acc, off);
        od      += __shfl_xor(od, off);
    }
    if (lane == 0) { wred[0][wave] = pos_acc; wred[1][wave] = neg_acc; wred[2][wave] = od; }
    __syncthreads();
    if (tid == 0) {
        float p = 0.f, n = 0.f, o = 0.f;
        #pragma unroll
        for (int w = 0; w < TPB / 64; ++w) { p += wred[0][w]; n += wred[1][w]; o += wred[2][w]; }
        atomicAdd(&acc[0],  p);
        atomicAdd(&acc[16], n);
        atomicAdd(&acc[32], o);
    }
}

__global__ void cmfm_final(const int* __restrict__ labels, const float* __restrict__ acc,
                           float* __restrict__ out) {
    if (threadIdx.x == 0) {
        int npos = 0;
        for (int i = 0; i < Bn; ++i) npos += (labels[i] == 0);
        const float pos_sum   = acc[0];
        const float neg_sum   = acc[16];
        const float cross_sum = acc[32];   // Sigma_{i!=j} Sigma_t cos_ij(t)  (== T * cross_cos sum)

        const float cnt_pos = (float)npos * (float)Tn;
        const float cnt_neg = (float)(Bn - npos) * (float)Tn + (float)Bn * (float)(Bn - 1);

        float loss = 0.f;
        if (npos > 0) loss += 2.0f * pos_sum / cnt_pos;                       // ALPHA
        loss += (2.0f * neg_sum + 1.0f * cross_sum / (float)Tn) / cnt_neg;    // BETA, GAMMA
        out[0] = loss;
    }
}

extern "C" void kernel_launch(void* const* d_in, const int* in_sizes, int n_in,
                              void* d_out, int out_size, void* d_ws, size_t ws_size,
                              hipStream_t stream) {
    const float* fv     = (const float*)d_in[0];
    const float* fa     = (const float*)d_in[1];
    const int*   labels = (const int*)d_in[2];
    float* acc = (float*)d_ws;        // [0]=pos_sum [16]=neg_sum [32]=cross_sum (line-padded)
    float* out = (float*)d_out;

    hipMemsetAsync(acc, 0, 64 * sizeof(float), stream);
    cmfm_main<<<NBLK, TPB, 0, stream>>>(fv, fa, labels, acc);
    cmfm_final<<<1, 64, 0, stream>>>(labels, acc, out);
}